// Round 14
// baseline (165.401 us; speedup 1.0000x reference)
//
#include <hip/hip_runtime.h>

// Problem: B=32, N=128, T=96, H=64, TF=24. All I/O float32.
// A_norm = ones(N,N)/N => every GCN output is the node-mean (node-uniform);
// model collapses to per-batch H-vectors. Node dim only in the initial mean
// and the final broadcast.
//
// R13 post-mortem: ODE wave issues only ~60% of cycles (VALUBusy 2.4-2.9%
// vs 3.1% single-SIMD ceiling) => ~40% stall slots, and the issue side
// (32 dot2 + 32 readlane / layer) is already structurally minimal.
// R14: 2 batches per block (grid 16), wave 0 advances BOTH batches' RK4
// chains in one interleaved stream (shared packed-f16 weights) — chain B
// fills chain A's stall slots. Phase 1 does 2 batches (48 t/wave).

#define BN 32
#define NN 128
#define TT 96
#define HH 64
#define TFC 24

#if defined(__has_builtin)
#if __has_builtin(__builtin_amdgcn_fdot2)
#define HAVE_FDOT2 1
#endif
#if __has_builtin(__builtin_amdgcn_update_dpp)
#define HAVE_DPP 1
#endif
#endif

using half2v = __fp16 __attribute__((ext_vector_type(2)));

__device__ __forceinline__ unsigned pack_pair(float a, float b) {
    union { half2v h; unsigned u; } c;
    c.h = __builtin_amdgcn_cvt_pkrtz(a, b);
    return c.u;
}
__device__ __forceinline__ half2v as_h2(unsigned u) {
    union { unsigned u; half2v h; } c; c.u = u; return c.h;
}
__device__ __forceinline__ unsigned rdlu(unsigned v, int l) {
    return (unsigned)__builtin_amdgcn_readlane((int)v, l);
}
__device__ __forceinline__ float rdl(float v, int l) {
    return __int_as_float(__builtin_amdgcn_readlane(__float_as_int(v), l));
}

template <int CTRL>
__device__ __forceinline__ float dppf(float x) {
#if HAVE_DPP
    return __int_as_float(
        __builtin_amdgcn_update_dpp(0, __float_as_int(x), CTRL, 0xF, 0xF, true));
#else
    return 0.f;  // unused
#endif
}

// xor-1 neighbor exchange on the VALU pipe (quad_perm [1,0,3,2]).
__device__ __forceinline__ float xor1(float x) {
#if HAVE_DPP
    return dppf<0xB1>(x);
#else
    return __shfl_xor(x, 1, 64);
#endif
}

__device__ __forceinline__ float wave_sum(float v) {
#if HAVE_DPP
    v += dppf<0xB1>(v);            // xor1
    v += dppf<0x4E>(v);            // xor2
    v += dppf<0x141>(v);           // row_half_mirror
    v += dppf<0x140>(v);           // row_mirror
    return ((rdl(v, 0) + rdl(v, 16)) + (rdl(v, 32) + rdl(v, 48)));
#else
#pragma unroll
    for (int off = 32; off > 0; off >>= 1) v += __shfl_xor(v, off, 64);
    return v;
#endif
}
// Two interleaved wave sums: the chains hide each other's DPP latency.
__device__ __forceinline__ void wave_sum2(float& a, float& b) {
#if HAVE_DPP
    a += dppf<0xB1>(a);  b += dppf<0xB1>(b);
    a += dppf<0x4E>(a);  b += dppf<0x4E>(b);
    a += dppf<0x141>(a); b += dppf<0x141>(b);
    a += dppf<0x140>(a); b += dppf<0x140>(b);
    a = (rdl(a, 0) + rdl(a, 16)) + (rdl(a, 32) + rdl(a, 48));
    b = (rdl(b, 0) + rdl(b, 16)) + (rdl(b, 32) + rdl(b, 48));
#else
    a = wave_sum(a); b = wave_sum(b);
#endif
}
__device__ __forceinline__ float wave_max(float v) {
#if HAVE_DPP
    v = fmaxf(v, dppf<0xB1>(v));
    v = fmaxf(v, dppf<0x4E>(v));
    v = fmaxf(v, dppf<0x141>(v));
    v = fmaxf(v, dppf<0x140>(v));
    return fmaxf(fmaxf(rdl(v, 0), rdl(v, 16)), fmaxf(rdl(v, 32), rdl(v, 48)));
#else
#pragma unroll
    for (int off = 32; off > 0; off >>= 1) v = fmaxf(v, __shfl_xor(v, off, 64));
    return v;
#endif
}

__device__ __forceinline__ float dot2acc(unsigned w, unsigned up, float acc) {
#if HAVE_FDOT2
    return __builtin_amdgcn_fdot2(as_h2(w), as_h2(up), acc, false);
#else
    const half2v wh = as_h2(w), uh = as_h2(up);
    return fmaf((float)wh.y, (float)uh.y, fmaf((float)wh.x, (float)uh.x, acc));
#endif
}

// Dual-stream 64-MAC matvec (shared weights): two independent chains
// interleaved => each fills the other's stall slots.
#define PMV64_2(WP, UA, UB, RA, RB)                                        \
    do {                                                                   \
        float a0 = 0.f, a1 = 0.f, a2 = 0.f, a3 = 0.f;                      \
        float b0 = 0.f, b1 = 0.f, b2 = 0.f, b3 = 0.f;                      \
        _Pragma("unroll")                                                  \
        for (int k = 0; k < 32; k += 4) {                                  \
            const unsigned ua0 = rdlu(UA, 2 * k);                          \
            const unsigned ub0 = rdlu(UB, 2 * k);                          \
            const unsigned ua1 = rdlu(UA, 2 * k + 2);                      \
            const unsigned ub1 = rdlu(UB, 2 * k + 2);                      \
            const unsigned ua2 = rdlu(UA, 2 * k + 4);                      \
            const unsigned ub2 = rdlu(UB, 2 * k + 4);                      \
            const unsigned ua3 = rdlu(UA, 2 * k + 6);                      \
            const unsigned ub3 = rdlu(UB, 2 * k + 6);                      \
            a0 = dot2acc(WP[k],     ua0, a0);                              \
            b0 = dot2acc(WP[k],     ub0, b0);                              \
            a1 = dot2acc(WP[k + 1], ua1, a1);                              \
            b1 = dot2acc(WP[k + 1], ub1, b1);                              \
            a2 = dot2acc(WP[k + 2], ua2, a2);                              \
            b2 = dot2acc(WP[k + 2], ub2, b2);                              \
            a3 = dot2acc(WP[k + 3], ua3, a3);                              \
            b3 = dot2acc(WP[k + 3], ub3, b3);                              \
        }                                                                  \
        RA = (a0 + a1) + (a2 + a3);                                        \
        RB = (b0 + b1) + (b2 + b3);                                        \
    } while (0)

// No clamp: x->+inf => e=inf => rcp=0 => 1; x->-inf => e=0 => 1-2 = -1.
__device__ __forceinline__ float fast_tanh(float x) {
    float e = __expf(2.f * x);
    return 1.f - 2.f * __builtin_amdgcn_rcpf(e + 1.f);
}
__device__ __forceinline__ float fast_sigmoid(float x) {
    return __builtin_amdgcn_rcpf(1.f + __expf(-x));
}

__global__ __launch_bounds__(256, 1)
void fused_kernel(
    const float* __restrict__ x,    const float* __restrict__ Ws1,
    const float* __restrict__ bs1,  const float* __restrict__ Ws2,
    const float* __restrict__ bs2,  const float* __restrict__ Wa1,
    const float* __restrict__ ba1,  const float* __restrict__ Wa2,
    const float* __restrict__ Wih,  const float* __restrict__ bih,
    const float* __restrict__ bhh,  const float* __restrict__ Wo1,
    const float* __restrict__ bo1p, const float* __restrict__ Wo2,
    const float* __restrict__ bo2p, const float* __restrict__ Wout,
    const float* __restrict__ boutp, float* __restrict__ out)
{
    const int tid  = threadIdx.x;
    const int lane = tid & 63;
    const int w    = tid >> 6;
    const int b0   = 2 * blockIdx.x;      // this block's two batches
    const int b1   = b0 + 1;

    __shared__ float xbar2[2][TT];
    __shared__ float h2s[2][TT][HH];      // 48 KB
    __shared__ float atts[2][TT];

    // ---- phase 0: xbar for both batches ----
    if (tid < 2 * TT) {
        const int bi = tid / TT;
        const int t  = tid - bi * TT;
        const float* xb = x + (size_t)(b0 + bi) * NN * TT + t;
        float s = 0.f;
#pragma unroll
        for (int n = 0; n < NN; ++n) s += xb[n * TT];
        xbar2[bi][t] = s * (1.f / 128.f);
    }

    {   // ---- phase 1: wave w owns batch (w>>1), t in [(w&1)*48, +48) ----
        const float ws1l = Ws1[lane];
        const float bs1l = bs1[lane];
        const float bs2l = bs2[lane];
        const float ba1l = ba1[lane];
        const float wa2l = Wa2[lane];
        unsigned ws2p[32], wa1p[32];
#pragma unroll
        for (int k = 0; k < 32; ++k) {
            ws2p[k] = pack_pair(Ws2[(2 * k) * HH + lane], Ws2[(2 * k + 1) * HH + lane]);
            wa1p[k] = pack_pair(Wa1[(2 * k) * HH + lane], Wa1[(2 * k + 1) * HH + lane]);
        }
#pragma unroll
        for (int k = 0; k < 32; ++k) {
            asm volatile("" : "+v"(ws2p[k]), "+v"(wa1p[k]));  // pin: 64 VGPRs
        }
        __syncthreads();   // barrier 1: xbar ready

        const int bb = w >> 1;
        const int tb = (w & 1) * 48;
#pragma unroll 1
        for (int i = 0; i < 24; ++i) {
            const int t0 = tb + 2 * i;
            const int t1 = t0 + 1;
            const float sA = xbar2[bb][t0];
            const float sB = xbar2[bb][t1];
            const float h1A = fmaxf(fmaf(sA, ws1l, bs1l), 0.f);
            const float h1B = fmaxf(fmaf(sB, ws1l, bs1l), 0.f);
            const unsigned uA = pack_pair(h1A, xor1(h1A));
            const unsigned uB = pack_pair(h1B, xor1(h1B));
            float accA, accB;
            PMV64_2(ws2p, uA, uB, accA, accB);
            const float h2A = fmaxf(accA + bs2l, 0.f);
            const float h2B = fmaxf(accB + bs2l, 0.f);
            h2s[bb][t0][lane] = h2A;
            h2s[bb][t1][lane] = h2B;

            const unsigned vA = pack_pair(h2A, xor1(h2A));
            const unsigned vB = pack_pair(h2B, xor1(h2B));
            PMV64_2(wa1p, vA, vB, accA, accB);
            float gA = fast_tanh(accA + ba1l) * wa2l;
            float gB = fast_tanh(accB + ba1l) * wa2l;
            wave_sum2(gA, gB);                        // ba2: shift-invariant
            if (lane == 0) { atts[bb][t0] = gA; atts[bb][t1] = gB; }
        }
    }
    __syncthreads();   // barrier 2: h2s, atts ready

    if (w != 0) return;   // waves 1-3 retire

    // ============ wave 0: softmax + nf + GRU for BOTH batches ============
    float yv[2];
#pragma unroll 1
    for (int bi = 0; bi < 2; ++bi) {
        const float a0s = atts[bi][lane];
        const float a1s = (lane < TT - 64) ? atts[bi][64 + lane] : -1e30f;
        const float m = wave_max(fmaxf(a0s, a1s));
        const float e0 = __expf(a0s - m);
        const float e1 = (lane < TT - 64) ? __expf(a1s - m) : 0.f;
        const float inv = __builtin_amdgcn_rcpf(wave_sum(e0 + e1));
        const float q0 = e0 * inv;
        const float q1 = e1 * inv;

        float nf = 0.f;
#pragma unroll
        for (int t = 0; t < 64; ++t) nf = fmaf(rdl(q0, t), h2s[bi][t][lane], nf);
#pragma unroll
        for (int t = 0; t < 32; ++t) nf = fmaf(rdl(q1, t), h2s[bi][64 + t][lane], nf);

        // one-step GRU, h0=0 (W_hh matmul vanishes; b_hh biases remain)
        float gr = bih[lane];
        float gz = bih[64 + lane];
        float gn = bih[128 + lane];
#pragma unroll
        for (int j = 0; j < HH; j += 4) {
            const float4 wr = *(const float4*)&Wih[(size_t)lane * HH + j];
            const float4 wz = *(const float4*)&Wih[(size_t)(64 + lane) * HH + j];
            const float4 wn = *(const float4*)&Wih[(size_t)(128 + lane) * HH + j];
            const float n0 = rdl(nf, j), n1 = rdl(nf, j + 1);
            const float n2 = rdl(nf, j + 2), n3 = rdl(nf, j + 3);
            gr += n0 * wr.x + n1 * wr.y + n2 * wr.z + n3 * wr.w;
            gz += n0 * wz.x + n1 * wz.y + n2 * wz.z + n3 * wz.w;
            gn += n0 * wn.x + n1 * wn.y + n2 * wn.z + n3 * wn.w;
        }
        const float r = fast_sigmoid(gr + bhh[lane]);
        const float z = fast_sigmoid(gz + bhh[64 + lane]);
        const float n = fast_tanh(gn + r * bhh[128 + lane]);
        yv[bi] = (1.f - z) * n;
    }
    float y0 = yv[0], y1 = yv[1];

    // ---- ODE weights: packed f16 into 64 pinned VGPRs ----
    unsigned w1p[32], w2p[32];
#pragma unroll
    for (int k = 0; k < 32; ++k) {
        w1p[k] = pack_pair(Wo1[(2 * k) * HH + lane], Wo1[(2 * k + 1) * HH + lane]);
        w2p[k] = pack_pair(Wo2[(2 * k) * HH + lane], Wo2[(2 * k + 1) * HH + lane]);
    }
#pragma unroll
    for (int k = 0; k < 32; ++k) {
        asm volatile("" : "+v"(w1p[k]), "+v"(w2p[k]));
    }
    const float bo1 = bo1p[lane];
    const float bo2 = bo2p[lane];
    const float wo  = Wout[lane];
    const float bo  = boutp[0];

    // dual f(u): both batches' layers interleaved, shared weights.
    auto f_eval2 = [&](float uA, float uB, float& rA, float& rB) {
        const unsigned pA = pack_pair(uA, xor1(uA));
        const unsigned pB = pack_pair(uB, xor1(uB));
        float aA, aB;
        PMV64_2(w1p, pA, pB, aA, aB);
        const float vA = fast_tanh(aA + bo1);
        const float vB = fast_tanh(aB + bo1);
        const unsigned qA = pack_pair(vA, xor1(vA));
        const unsigned qB = pack_pair(vB, xor1(vB));
        PMV64_2(w2p, qA, qB, aA, aB);
        rA = fast_tanh(aA + bo2);
        rB = fast_tanh(aB + bo2);
    };

    float* ob0 = out + (size_t)b0 * NN * TFC;
    float* ob1 = out + (size_t)b1 * NN * TFC;
    {
        float p0 = y0 * wo, p1 = y1 * wo;
        wave_sum2(p0, p1);
        p0 += bo; p1 += bo;                          // traj[0] = hidden
        ob0[lane * TFC]        = p0;
        ob0[(64 + lane) * TFC] = p0;
        ob1[lane * TFC]        = p1;
        ob1[(64 + lane) * TFC] = p1;
    }

    const float dt = (float)(24.0 / 23.0);
    const float third = 1.f / 3.f;

#pragma unroll 1
    for (int st = 0; st < TFC - 1; ++st) {
        float k1A, k1B, k2A, k2B, k3A, k3B, k4A, k4B;
        f_eval2(y0, y1, k1A, k1B);
        f_eval2(y0 + dt * k1A * third, y1 + dt * k1B * third, k2A, k2B);
        f_eval2(y0 + dt * (k2A - k1A * third), y1 + dt * (k2B - k1B * third),
                k3A, k3B);
        f_eval2(y0 + dt * (k1A - k2A + k3A), y1 + dt * (k1B - k2B + k3B),
                k4A, k4B);
        y0 = y0 + dt * (k1A + 3.f * (k2A + k3A) + k4A) * 0.125f;
        y1 = y1 + dt * (k1B + 3.f * (k2B + k3B) + k4B) * 0.125f;
        float p0 = y0 * wo, p1 = y1 * wo;
        wave_sum2(p0, p1);
        p0 += bo; p1 += bo;
        ob0[lane * TFC + st + 1]        = p0;
        ob0[(64 + lane) * TFC + st + 1] = p0;
        ob1[lane * TFC + st + 1]        = p1;
        ob1[(64 + lane) * TFC + st + 1] = p1;
    }
}

extern "C" void kernel_launch(void* const* d_in, const int* in_sizes, int n_in,
                              void* d_out, int out_size, void* d_ws, size_t ws_size,
                              hipStream_t stream) {
    (void)in_sizes; (void)n_in; (void)d_ws; (void)ws_size; (void)out_size;
    const float* x    = (const float*)d_in[0];
    const float* Ws1  = (const float*)d_in[1];
    const float* bs1  = (const float*)d_in[2];
    const float* Ws2  = (const float*)d_in[3];
    const float* bs2  = (const float*)d_in[4];
    const float* Wa1  = (const float*)d_in[5];
    const float* ba1  = (const float*)d_in[6];
    const float* Wa2  = (const float*)d_in[7];
    // d_in[8]  = ba2  : unused (softmax shift-invariant)
    const float* Wih  = (const float*)d_in[9];
    // d_in[10] = W_hh : unused (h0 = 0)
    const float* bih  = (const float*)d_in[11];
    const float* bhh  = (const float*)d_in[12];
    const float* Wo1  = (const float*)d_in[13];
    const float* bo1  = (const float*)d_in[14];
    const float* Wo2  = (const float*)d_in[15];
    const float* bo2  = (const float*)d_in[16];
    const float* Wout = (const float*)d_in[17];
    const float* bout = (const float*)d_in[18];

    fused_kernel<<<dim3(BN / 2), dim3(256), 0, stream>>>(
        x, Ws1, bs1, Ws2, bs2, Wa1, ba1, Wa2,
        Wih, bih, bhh, Wo1, bo1, Wo2, bo2, Wout, bout,
        (float*)d_out);
}

// Round 15
// 125.181 us; speedup vs baseline: 1.3213x; 1.3213x over previous
//
#include <hip/hip_runtime.h>

// Problem: B=32, N=128, T=96, H=64, TF=24. All I/O float32.
// A_norm = ones(N,N)/N => every GCN output is the node-mean (node-uniform);
// model collapses to per-batch H-vectors. Node dim only in the initial mean
// and the final broadcast.
//
// R14 post-mortem: dual-ODE interleave was free (chain has hideable latency
// bubbles) but can't shorten wall time; the +16us came from doubling
// phase-1 per-wave work. R15: (1) SPLIT kernels — phase 0/1 gets 4x more
// blocks (4us wall), staging h2 (packed f16 t-pairs) + atts via d_ws
// (~406KB); (2) ODE matvec issues ALL 32 readlanes first (SGPR-parked,
// no deps), then 32 dot2s — max producer-consumer distance removes the
// per-pair hazard bubbles that dual-interleave proved are hideable.

#define BN 32
#define NN 128
#define TT 96
#define HH 64
#define TFC 24

#if defined(__has_builtin)
#if __has_builtin(__builtin_amdgcn_fdot2)
#define HAVE_FDOT2 1
#endif
#if __has_builtin(__builtin_amdgcn_update_dpp)
#define HAVE_DPP 1
#endif
#endif

using half2v = __fp16 __attribute__((ext_vector_type(2)));

__device__ __forceinline__ unsigned pack_pair(float a, float b) {
    union { half2v h; unsigned u; } c;
    c.h = __builtin_amdgcn_cvt_pkrtz(a, b);
    return c.u;
}
__device__ __forceinline__ half2v as_h2(unsigned u) {
    union { unsigned u; half2v h; } c; c.u = u; return c.h;
}
__device__ __forceinline__ unsigned rdlu(unsigned v, int l) {
    return (unsigned)__builtin_amdgcn_readlane((int)v, l);
}
__device__ __forceinline__ float rdl(float v, int l) {
    return __int_as_float(__builtin_amdgcn_readlane(__float_as_int(v), l));
}

template <int CTRL>
__device__ __forceinline__ float dppf(float x) {
#if HAVE_DPP
    return __int_as_float(
        __builtin_amdgcn_update_dpp(0, __float_as_int(x), CTRL, 0xF, 0xF, true));
#else
    return 0.f;  // unused
#endif
}

__device__ __forceinline__ float xor1(float x) {
#if HAVE_DPP
    return dppf<0xB1>(x);          // quad_perm [1,0,3,2] — VALU pipe
#else
    return __shfl_xor(x, 1, 64);
#endif
}

__device__ __forceinline__ float wave_sum(float v) {
#if HAVE_DPP
    v += dppf<0xB1>(v);
    v += dppf<0x4E>(v);
    v += dppf<0x141>(v);
    v += dppf<0x140>(v);
    return ((rdl(v, 0) + rdl(v, 16)) + (rdl(v, 32) + rdl(v, 48)));
#else
#pragma unroll
    for (int off = 32; off > 0; off >>= 1) v += __shfl_xor(v, off, 64);
    return v;
#endif
}
__device__ __forceinline__ void wave_sum2(float& a, float& b) {
#if HAVE_DPP
    a += dppf<0xB1>(a);  b += dppf<0xB1>(b);
    a += dppf<0x4E>(a);  b += dppf<0x4E>(b);
    a += dppf<0x141>(a); b += dppf<0x141>(b);
    a += dppf<0x140>(a); b += dppf<0x140>(b);
    a = (rdl(a, 0) + rdl(a, 16)) + (rdl(a, 32) + rdl(a, 48));
    b = (rdl(b, 0) + rdl(b, 16)) + (rdl(b, 32) + rdl(b, 48));
#else
    a = wave_sum(a); b = wave_sum(b);
#endif
}
__device__ __forceinline__ float wave_max(float v) {
#if HAVE_DPP
    v = fmaxf(v, dppf<0xB1>(v));
    v = fmaxf(v, dppf<0x4E>(v));
    v = fmaxf(v, dppf<0x141>(v));
    v = fmaxf(v, dppf<0x140>(v));
    return fmaxf(fmaxf(rdl(v, 0), rdl(v, 16)), fmaxf(rdl(v, 32), rdl(v, 48)));
#else
#pragma unroll
    for (int off = 32; off > 0; off >>= 1) v = fmaxf(v, __shfl_xor(v, off, 64));
    return v;
#endif
}

__device__ __forceinline__ float dot2acc(unsigned w, unsigned up, float acc) {
#if HAVE_FDOT2
    return __builtin_amdgcn_fdot2(as_h2(w), as_h2(up), acc, false);
#else
    const half2v wh = as_h2(w), uh = as_h2(up);
    return fmaf((float)wh.y, (float)uh.y, fmaf((float)wh.x, (float)uh.x, acc));
#endif
}

// 64-MAC matvec: ALL 32 readlanes issue first (SGPR-parked, no deps),
// then 32 dot2s — max distance kills the rdl->dot2 latency bubbles.
#define PMV64(WP, UPACK, RES)                                              \
    do {                                                                   \
        unsigned us_[32];                                                  \
        _Pragma("unroll")                                                  \
        for (int k = 0; k < 32; ++k) us_[k] = rdlu(UPACK, 2 * k);          \
        float c0 = 0.f, c1 = 0.f, c2 = 0.f, c3 = 0.f;                      \
        _Pragma("unroll")                                                  \
        for (int k = 0; k < 32; k += 4) {                                  \
            c0 = dot2acc(WP[k],     us_[k],     c0);                       \
            c1 = dot2acc(WP[k + 1], us_[k + 1], c1);                       \
            c2 = dot2acc(WP[k + 2], us_[k + 2], c2);                       \
            c3 = dot2acc(WP[k + 3], us_[k + 3], c3);                       \
        }                                                                  \
        RES = (c0 + c1) + (c2 + c3);                                       \
    } while (0)

// Dual-stream matvec (shared weights) for phase 1.
#define PMV64_2(WP, UA, UB, RA, RB)                                        \
    do {                                                                   \
        float a0 = 0.f, a1 = 0.f, a2 = 0.f, a3 = 0.f;                      \
        float b0 = 0.f, b1 = 0.f, b2 = 0.f, b3 = 0.f;                      \
        _Pragma("unroll")                                                  \
        for (int k = 0; k < 32; k += 4) {                                  \
            const unsigned ua0 = rdlu(UA, 2 * k);                          \
            const unsigned ub0 = rdlu(UB, 2 * k);                          \
            const unsigned ua1 = rdlu(UA, 2 * k + 2);                      \
            const unsigned ub1 = rdlu(UB, 2 * k + 2);                      \
            const unsigned ua2 = rdlu(UA, 2 * k + 4);                      \
            const unsigned ub2 = rdlu(UB, 2 * k + 4);                      \
            const unsigned ua3 = rdlu(UA, 2 * k + 6);                      \
            const unsigned ub3 = rdlu(UB, 2 * k + 6);                      \
            a0 = dot2acc(WP[k],     ua0, a0);                              \
            b0 = dot2acc(WP[k],     ub0, b0);                              \
            a1 = dot2acc(WP[k + 1], ua1, a1);                              \
            b1 = dot2acc(WP[k + 1], ub1, b1);                              \
            a2 = dot2acc(WP[k + 2], ua2, a2);                              \
            b2 = dot2acc(WP[k + 2], ub2, b2);                              \
            a3 = dot2acc(WP[k + 3], ua3, a3);                              \
            b3 = dot2acc(WP[k + 3], ub3, b3);                              \
        }                                                                  \
        RA = (a0 + a1) + (a2 + a3);                                        \
        RB = (b0 + b1) + (b2 + b3);                                        \
    } while (0)

// No clamp: x->+inf => rcp(inf)=0 => 1; x->-inf => e=0 => -1. (R13-proven)
__device__ __forceinline__ float fast_tanh(float x) {
    float e = __expf(2.f * x);
    return 1.f - 2.f * __builtin_amdgcn_rcpf(e + 1.f);
}
__device__ __forceinline__ float fast_sigmoid(float x) {
    return __builtin_amdgcn_rcpf(1.f + __expf(-x));
}

// ============================ Kernel A ====================================
// grid (4, 32): block = (t-quarter, batch). 4 waves x 6 t (3 dual-iters).
// Writes h2 as packed f16 t-pairs and att logits to workspace.
__global__ __launch_bounds__(256) void spatial_kernel(
    const float* __restrict__ x,    const float* __restrict__ Ws1,
    const float* __restrict__ bs1,  const float* __restrict__ Ws2,
    const float* __restrict__ bs2,  const float* __restrict__ Wa1,
    const float* __restrict__ ba1,  const float* __restrict__ Wa2,
    unsigned* __restrict__ ws_h2,   float* __restrict__ ws_att)
{
    const int tid  = threadIdx.x;
    const int lane = tid & 63;
    const int w    = tid >> 6;
    const int tq   = blockIdx.x;
    const int b    = blockIdx.y;
    const int tbase = tq * 24;

    __shared__ float xbar[24];
    if (tid < 24) {
        const float* xb = x + (size_t)b * NN * TT + (tbase + tid);
        float s = 0.f;
#pragma unroll
        for (int n = 0; n < NN; ++n) s += xb[n * TT];
        xbar[tid] = s * (1.f / 128.f);
    }

    const float ws1l = Ws1[lane];
    const float bs1l = bs1[lane];
    const float bs2l = bs2[lane];
    const float ba1l = ba1[lane];
    const float wa2l = Wa2[lane];
    unsigned ws2p[32], wa1p[32];
#pragma unroll
    for (int k = 0; k < 32; ++k) {
        ws2p[k] = pack_pair(Ws2[(2 * k) * HH + lane], Ws2[(2 * k + 1) * HH + lane]);
        wa1p[k] = pack_pair(Wa1[(2 * k) * HH + lane], Wa1[(2 * k + 1) * HH + lane]);
    }
#pragma unroll
    for (int k = 0; k < 32; ++k) {
        asm volatile("" : "+v"(ws2p[k]), "+v"(wa1p[k]));
    }
    __syncthreads();   // xbar ready

#pragma unroll 1
    for (int i = 0; i < 3; ++i) {
        const int tl0 = w * 6 + 2 * i;          // local t (even)
        const float sA = xbar[tl0];
        const float sB = xbar[tl0 + 1];
        const float h1A = fmaxf(fmaf(sA, ws1l, bs1l), 0.f);
        const float h1B = fmaxf(fmaf(sB, ws1l, bs1l), 0.f);
        const unsigned uA = pack_pair(h1A, xor1(h1A));
        const unsigned uB = pack_pair(h1B, xor1(h1B));
        float accA, accB;
        PMV64_2(ws2p, uA, uB, accA, accB);
        const float h2A = fmaxf(accA + bs2l, 0.f);
        const float h2B = fmaxf(accB + bs2l, 0.f);
        // h2 pair over adjacent t: element tp = (tbase+tl0)/2
        ws_h2[((size_t)b * (TT / 2) + (tbase + tl0) / 2) * HH + lane] =
            pack_pair(h2A, h2B);

        const unsigned vA = pack_pair(h2A, xor1(h2A));
        const unsigned vB = pack_pair(h2B, xor1(h2B));
        PMV64_2(wa1p, vA, vB, accA, accB);
        float gA = fast_tanh(accA + ba1l) * wa2l;
        float gB = fast_tanh(accB + ba1l) * wa2l;
        wave_sum2(gA, gB);                       // ba2: shift-invariant
        if (lane == 0) {
            ws_att[b * TT + tbase + tl0]     = gA;
            ws_att[b * TT + tbase + tl0 + 1] = gB;
        }
    }
}

// ============================ Kernel B ====================================
// grid 32 x 64 threads: softmax + nf + GRU + 23 RK4 steps + head.
__global__ __launch_bounds__(64)
__attribute__((amdgpu_waves_per_eu(1, 1)))
void ode_kernel(
    const unsigned* __restrict__ ws_h2, const float* __restrict__ ws_att,
    const float* __restrict__ Wih,  const float* __restrict__ bih,
    const float* __restrict__ bhh,  const float* __restrict__ Wo1,
    const float* __restrict__ bo1p, const float* __restrict__ Wo2,
    const float* __restrict__ bo2p, const float* __restrict__ Wout,
    const float* __restrict__ boutp, float* __restrict__ out)
{
    const int lane = threadIdx.x;
    const int b    = blockIdx.x;

    // ---- softmax over t (96 logits: lane t, lane 64+t for t<32) ----
    const float a0s = ws_att[b * TT + lane];
    const float a1s = (lane < TT - 64) ? ws_att[b * TT + 64 + lane] : -1e30f;
    const float m = wave_max(fmaxf(a0s, a1s));
    const float e0 = __expf(a0s - m);
    const float e1 = (lane < TT - 64) ? __expf(a1s - m) : 0.f;
    const float inv = __builtin_amdgcn_rcpf(wave_sum(e0 + e1));
    const float q0 = e0 * inv;      // weight for t = lane
    const float q1 = e1 * inv;      // weight for t = 64 + lane (lane < 32)

    // ---- nf[lane] = sum_t w[t]*h2[t][lane] via packed t-pairs + dot2 ----
    const unsigned* h2b = ws_h2 + (size_t)b * (TT / 2) * HH;
    unsigned hp[TT / 2];
#pragma unroll
    for (int tp = 0; tp < TT / 2; ++tp) hp[tp] = h2b[tp * HH + lane];
    float nf = 0.f;
#pragma unroll
    for (int tp = 0; tp < 32; ++tp) {
        const unsigned qp = pack_pair(rdl(q0, 2 * tp), rdl(q0, 2 * tp + 1));
        nf = dot2acc(hp[tp], qp, nf);
    }
#pragma unroll
    for (int tp = 32; tp < TT / 2; ++tp) {
        const unsigned qp = pack_pair(rdl(q1, 2 * tp - 64), rdl(q1, 2 * tp - 63));
        nf = dot2acc(hp[tp], qp, nf);
    }

    // ---- one-step GRU, h0=0 (W_hh matmul vanishes; b_hh biases remain) ----
    float gr = bih[lane];
    float gz = bih[64 + lane];
    float gn = bih[128 + lane];
#pragma unroll
    for (int j = 0; j < HH; j += 4) {
        const float4 wr = *(const float4*)&Wih[(size_t)lane * HH + j];
        const float4 wz = *(const float4*)&Wih[(size_t)(64 + lane) * HH + j];
        const float4 wn = *(const float4*)&Wih[(size_t)(128 + lane) * HH + j];
        const float n0 = rdl(nf, j), n1 = rdl(nf, j + 1);
        const float n2 = rdl(nf, j + 2), n3 = rdl(nf, j + 3);
        gr += n0 * wr.x + n1 * wr.y + n2 * wr.z + n3 * wr.w;
        gz += n0 * wz.x + n1 * wz.y + n2 * wz.z + n3 * wz.w;
        gn += n0 * wn.x + n1 * wn.y + n2 * wn.z + n3 * wn.w;
    }
    const float r = fast_sigmoid(gr + bhh[lane]);
    const float z = fast_sigmoid(gz + bhh[64 + lane]);
    const float n = fast_tanh(gn + r * bhh[128 + lane]);
    float y = (1.f - z) * n;

    // ---- ODE weights: packed f16 into 64 pinned VGPRs ----
    unsigned w1p[32], w2p[32];
#pragma unroll
    for (int k = 0; k < 32; ++k) {
        w1p[k] = pack_pair(Wo1[(2 * k) * HH + lane], Wo1[(2 * k + 1) * HH + lane]);
        w2p[k] = pack_pair(Wo2[(2 * k) * HH + lane], Wo2[(2 * k + 1) * HH + lane]);
    }
#pragma unroll
    for (int k = 0; k < 32; ++k) {
        asm volatile("" : "+v"(w1p[k]), "+v"(w2p[k]));
    }
    const float bo1 = bo1p[lane];
    const float bo2 = bo2p[lane];
    const float wo  = Wout[lane];
    const float bo  = boutp[0];

    auto f_eval = [&](float u) -> float {
        const unsigned upA = pack_pair(u, xor1(u));
        float acc;
        PMV64(w1p, upA, acc);
        const float v = fast_tanh(acc + bo1);
        const unsigned upB = pack_pair(v, xor1(v));
        PMV64(w2p, upB, acc);
        return fast_tanh(acc + bo2);
    };

    float* ob = out + (size_t)b * NN * TFC;
    {
        const float p = wave_sum(y * wo) + bo;     // traj[0] = hidden
        ob[lane * TFC]        = p;
        ob[(64 + lane) * TFC] = p;
    }

    const float dt = (float)(24.0 / 23.0);
    const float third = 1.f / 3.f;

#pragma unroll 1
    for (int st = 0; st < TFC - 1; ++st) {
        const float k1 = f_eval(y);
        const float k2 = f_eval(y + dt * k1 * third);
        const float k3 = f_eval(y + dt * (k2 - k1 * third));
        const float k4 = f_eval(y + dt * (k1 - k2 + k3));
        y = y + dt * (k1 + 3.f * (k2 + k3) + k4) * 0.125f;
        const float p = wave_sum(y * wo) + bo;
        ob[lane * TFC + st + 1]        = p;
        ob[(64 + lane) * TFC + st + 1] = p;
    }
}

extern "C" void kernel_launch(void* const* d_in, const int* in_sizes, int n_in,
                              void* d_out, int out_size, void* d_ws, size_t ws_size,
                              hipStream_t stream) {
    (void)in_sizes; (void)n_in; (void)ws_size; (void)out_size;
    const float* x    = (const float*)d_in[0];
    const float* Ws1  = (const float*)d_in[1];
    const float* bs1  = (const float*)d_in[2];
    const float* Ws2  = (const float*)d_in[3];
    const float* bs2  = (const float*)d_in[4];
    const float* Wa1  = (const float*)d_in[5];
    const float* ba1  = (const float*)d_in[6];
    const float* Wa2  = (const float*)d_in[7];
    // d_in[8]  = ba2  : unused (softmax shift-invariant)
    const float* Wih  = (const float*)d_in[9];
    // d_in[10] = W_hh : unused (h0 = 0)
    const float* bih  = (const float*)d_in[11];
    const float* bhh  = (const float*)d_in[12];
    const float* Wo1  = (const float*)d_in[13];
    const float* bo1  = (const float*)d_in[14];
    const float* Wo2  = (const float*)d_in[15];
    const float* bo2  = (const float*)d_in[16];
    const float* Wout = (const float*)d_in[17];
    const float* bout = (const float*)d_in[18];

    unsigned* ws_h2 = (unsigned*)d_ws;                       // 32*48*64*4 = 384KB
    float* ws_att   = (float*)((char*)d_ws + (size_t)BN * (TT / 2) * HH * 4);

    spatial_kernel<<<dim3(4, BN), dim3(256), 0, stream>>>(
        x, Ws1, bs1, Ws2, bs2, Wa1, ba1, Wa2, ws_h2, ws_att);

    ode_kernel<<<dim3(BN), dim3(64), 0, stream>>>(
        ws_h2, ws_att, Wih, bih, bhh, Wo1, bo1, Wo2, bo2, Wout, bout,
        (float*)d_out);
}